// Round 2
// baseline (5394.540 us; speedup 1.0000x reference)
//
#include <hip/hip_runtime.h>
#include <cstdint>
#include <cstddef>

#define LK(x) ((x) > 0.f ? (x) : 0.01f * (x))

constexpr int B_ = 256;
constexpr int N_ = 256;
constexpr int BN = B_ * N_;
constexpr int KNN = 4;
constexpr int CHUNK_B = 32;                 // batches per U/V chunk
constexpr int CHUNK_ROWS = CHUNK_B * N_;    // 8192 rows

// ---------------- KNN: one block per batch, one thread per point ----------------
__global__ void knn_kernel(const float* __restrict__ feat, int F, int* __restrict__ idxout) {
  __shared__ float px[N_], py[N_], pz[N_];
  int b = blockIdx.x, t = threadIdx.x;
  const float* row = feat + ((size_t)b * N_ + t) * F;
  px[t] = row[0]; py[t] = row[1]; pz[t] = row[2];
  __syncthreads();
  float x = px[t], y = py[t], z = pz[t];
  float bd0 = INFINITY, bd1 = INFINITY, bd2 = INFINITY, bd3 = INFINITY;
  int bi0 = 0, bi1 = 0, bi2 = 0, bi3 = 0;
  for (int j = 0; j < N_; ++j) {
    #pragma clang fp contract(off)
    float dx = x - px[j], dy = y - py[j], dz = z - pz[j];
    float d = (dx * dx + dy * dy) + dz * dz;
    if (j == t) continue;                 // self excluded (eye -> inf)
    if (d < bd3) {                        // strict <  == top_k lower-index tie-break
      if (d < bd2) {
        bd3 = bd2; bi3 = bi2;
        if (d < bd1) {
          bd2 = bd1; bi2 = bi1;
          if (d < bd0) { bd1 = bd0; bi1 = bi0; bd0 = d; bi0 = j; }
          else         { bd1 = d; bi1 = j; }
        } else         { bd2 = d; bi2 = j; }
      } else           { bd3 = d; bi3 = j; }
    }
  }
  int* o = idxout + ((size_t)b * N_ + t) * KNN;
  o[0] = bi0; o[1] = bi1; o[2] = bi2; o[3] = bi3;
}

// ---------------- wdiff = w1_top - w1_bot ----------------
__global__ void wdiff_kernel(const float* __restrict__ w1, int FH, float* __restrict__ wd) {
  int i = blockIdx.x * 256 + threadIdx.x;
  if (i < FH) wd[i] = w1[i] - w1[FH + i];
}

// ---------------- generic tiled fp32 GEMM: C (+)= act?(A) @ W (+ bias) --------
// BM=BN=64, BK=16, 256 threads (16x16), 4x4 micro-tile. M must be multiple of 64.
template<bool ACT_A, bool ACT_C, bool ACCUM, bool HAS_BIAS>
__global__ __launch_bounds__(256) void gemm_f32(
    const float* __restrict__ A, const float* __restrict__ W,
    const float* __restrict__ bias, float* __restrict__ C,
    int M, int N, int K) {
  __shared__ float sA[16][68];
  __shared__ float sW[16][68];
  int tid = threadIdx.x;
  int m0 = blockIdx.y * 64;
  int n0 = blockIdx.x * 64;
  int ty = tid >> 4, tx = tid & 15;
  int kkA = tid & 15, mA = tid >> 4;
  int nW = tid & 63, kW = tid >> 6;
  float acc[4][4] = {};
  for (int k0 = 0; k0 < K; k0 += 16) {
    #pragma unroll
    for (int i = 0; i < 4; ++i) {
      int m = mA + i * 16;
      int kg = k0 + kkA;
      float v = 0.f;
      if (kg < K) {
        v = A[(size_t)(m0 + m) * K + kg];
        if (ACT_A) v = LK(v);
      }
      sA[kkA][m] = v;
    }
    #pragma unroll
    for (int q = 0; q < 4; ++q) {
      int kk = kW + q * 4;
      int kg = k0 + kk;
      float v = 0.f;
      if (kg < K && (n0 + nW) < N) v = W[(size_t)kg * N + n0 + nW];
      sW[kk][nW] = v;
    }
    __syncthreads();
    #pragma unroll
    for (int kk = 0; kk < 16; ++kk) {
      float4 av = *(const float4*)&sA[kk][ty * 4];
      float4 wv = *(const float4*)&sW[kk][tx * 4];
      float a[4] = {av.x, av.y, av.z, av.w};
      float w[4] = {wv.x, wv.y, wv.z, wv.w};
      #pragma unroll
      for (int i = 0; i < 4; ++i)
        #pragma unroll
        for (int j = 0; j < 4; ++j)
          acc[i][j] += a[i] * w[j];
    }
    __syncthreads();
  }
  #pragma unroll
  for (int i = 0; i < 4; ++i) {
    int m = m0 + ty * 4 + i;
    #pragma unroll
    for (int j = 0; j < 4; ++j) {
      int n = n0 + tx * 4 + j;
      if (n < N) {
        float v = acc[i][j];
        if (HAS_BIAS) v += bias[n];
        if (ACT_C) v = LK(v);
        size_t off = (size_t)m * N + n;
        if (ACCUM) v += C[off];
        C[off] = v;
      }
    }
  }
}

// ---------------- fused edge stage 2 (chunk-local pointers) ----------------
// h1[edge] = leaky(U[i] + V[j])  (b1 folded into U);  out[i] = sum_k leaky(h1 @ w2 + b2)
// One block = 16 points = 64 edge rows. U/V/idx/out all point at the chunk base;
// chunks are whole batches so neighbor rows are chunk-local.
__global__ __launch_bounds__(256) void edge_stage2(
    const float* __restrict__ U, const float* __restrict__ V,
    const int* __restrict__ idx, const float* __restrict__ w2,
    const float* __restrict__ b2, float* __restrict__ out, int H1) {
  __shared__ float sH1[64][257];   // zero-padded cols up to 256
  __shared__ float sW[16][68];
  __shared__ int sJ[64];
  int tid = threadIdx.x;
  int g0 = blockIdx.x * 16;        // chunk-local first point row (16 | 256: no batch spanning)
  int bb = g0 >> 8;                // chunk-local batch index
  if (tid < 64) sJ[tid] = idx[(size_t)g0 * 4 + tid];
  __syncthreads();
  for (int r = 0; r < 64; ++r) {
    int gp = g0 + (r >> 2);
    int jrow = (bb << 8) + sJ[r];
    float v = 0.f;
    if (tid < H1) {
      float t = U[(size_t)gp * H1 + tid] + V[(size_t)jrow * H1 + tid];
      v = LK(t);
    }
    sH1[r][tid] = v;               // all 256 cols written (0 beyond H1)
  }
  __syncthreads();
  int ty = tid >> 4, tx = tid & 15;
  int nW = tid & 63, kW = tid >> 6;
  int nKt = (H1 + 15) >> 4;
  int gp = g0 + ty;                // this thread's point (its 4 micro-rows = its 4 edges)
  for (int ct = 0; ct < 3; ++ct) { // 192 = 3 * 64 col tiles
    float acc[4][4] = {};
    for (int kt = 0; kt < nKt; ++kt) {
      #pragma unroll
      for (int q = 0; q < 4; ++q) {
        int rowk = kt * 16 + kW + q * 4;
        float v = 0.f;
        if (rowk < H1) v = w2[(size_t)rowk * 192 + ct * 64 + nW];
        sW[kW + q * 4][nW] = v;
      }
      __syncthreads();
      #pragma unroll
      for (int kk = 0; kk < 16; ++kk) {
        int c = kt * 16 + kk;
        float4 wv = *(const float4*)&sW[kk][tx * 4];
        #pragma unroll
        for (int i = 0; i < 4; ++i) {
          float a = sH1[ty * 4 + i][c];
          acc[i][0] += a * wv.x; acc[i][1] += a * wv.y;
          acc[i][2] += a * wv.z; acc[i][3] += a * wv.w;
        }
      }
      __syncthreads();
    }
    #pragma unroll
    for (int j = 0; j < 4; ++j) {
      int col = ct * 64 + tx * 4 + j;
      float bv = b2[col];
      float s = 0.f;
      #pragma unroll
      for (int i = 0; i < 4; ++i) {
        float t = acc[i][j] + bv;
        s += LK(t);
      }
      out[(size_t)gp * 192 + col] = s;
    }
  }
}

// ---------------- pooling: max/min/sum/mean over N, then leaky ----------------
__global__ void pool_kernel(const float* __restrict__ h, float* __restrict__ pooled) {
  int b = blockIdx.x, ch = threadIdx.x;  // 192 threads
  const float* p = h + (size_t)b * N_ * 192 + ch;
  float mx = -INFINITY, mn = INFINITY, sm = 0.f;
  for (int n = 0; n < N_; ++n) {
    float v = p[(size_t)n * 192];
    mx = fmaxf(mx, v); mn = fminf(mn, v); sm += v;
  }
  float* o = pooled + (size_t)b * 768;
  o[ch]       = LK(mx);
  o[192 + ch] = LK(mn);
  o[384 + ch] = LK(sm);
  float mean = sm * (1.f / 256.f);
  o[576 + ch] = LK(mean);
}

// ---------------- head: nn3 (768->96) + leaky + nn4 (96->1) ----------------
__global__ void head_kernel(const float* __restrict__ pooled,
                            const float* __restrict__ w3, const float* __restrict__ b3,
                            const float* __restrict__ w4, const float* __restrict__ b4,
                            float* __restrict__ out) {
  __shared__ float sp[768];
  __shared__ float st[96];
  int b = blockIdx.x, t = threadIdx.x;   // 128 threads
  for (int c = t; c < 768; c += 128) sp[c] = pooled[(size_t)b * 768 + c];
  __syncthreads();
  if (t < 96) {
    float s = b3[t];
    for (int r = 0; r < 768; ++r) s += sp[r] * w3[(size_t)r * 96 + t];
    s = LK(s);
    st[t] = s * w4[t];
  }
  __syncthreads();
  if (t == 0) {
    float s = b4[0];
    for (int i = 0; i < 96; ++i) s += st[i];
    out[b] = s;
  }
}

extern "C" void kernel_launch(void* const* d_in, const int* in_sizes, int n_in,
                              void* d_out, int out_size, void* d_ws, size_t ws_size,
                              hipStream_t stream) {
  (void)in_sizes; (void)n_in; (void)out_size; (void)ws_size;
  const float* x = (const float*)d_in[0];
  const float* P[25];
  for (int i = 0; i < 25; ++i) P[i] = (const float*)d_in[i];

  // ---- workspace layout (peak ~185.3 MB; U/V chunked to keep it small) ----
  char* ws = (char*)d_ws;
  int*   idx    = (int*)  (ws + 0);            //  1,048,576 B
  float* A      = (float*)(ws + 1048576);      // 50,331,648 B (a, then c, then h2)
  float* Bb     = (float*)(ws + 51380224);     // 50,331,648 B (b, then d)
  float* h1     = (float*)(ws + 101711872);    // 66,060,288 B (nn1 accumulator)
  float* Ubuf   = (float*)(ws + 167772160);    //  8,257,536 B (chunk)
  float* Vbuf   = (float*)(ws + 176029696);    //  8,257,536 B (chunk)
  float* pooled = (float*)(ws + 184287232);    //    786,432 B
  float* wdiff  = (float*)(ws + 185073664);    //    193,536 B
  // end: 185,267,200 B

  auto edge_layer = [&](const float* src, int F, const float* w1, const float* b1,
                        const float* w2, const float* b2, float* dst, int H1) {
    knn_kernel<<<B_, N_, 0, stream>>>(src, F, idx);
    int FH = F * H1;
    wdiff_kernel<<<(FH + 255) / 256, 256, 0, stream>>>(w1, FH, wdiff);
    dim3 gU((H1 + 63) / 64, CHUNK_ROWS / 64);
    for (int cb = 0; cb < B_; cb += CHUNK_B) {
      size_t base = (size_t)cb * N_;
      // U = src @ (w1_top - w1_bot) + b1 ; V = src @ w1_bot   (chunk rows)
      gemm_f32<false, false, false, true ><<<gU, 256, 0, stream>>>(src + base * F, wdiff,   b1,      Ubuf, CHUNK_ROWS, H1, F);
      gemm_f32<false, false, false, false><<<gU, 256, 0, stream>>>(src + base * F, w1 + FH, nullptr, Vbuf, CHUNK_ROWS, H1, F);
      edge_stage2<<<CHUNK_ROWS / 16, 256, 0, stream>>>(Ubuf, Vbuf, idx + base * 4, w2, b2, dst + base * 192, H1);
    }
  };

  dim3 g1((252 + 63) / 64, BN / 64);

  // a = edge(x)
  edge_layer(x, 4, P[1], P[2], P[3], P[4], A, 96);
  // b = edge(a)
  edge_layer(A, 192, P[5], P[6], P[7], P[8], Bb, 252);
  // h1 = x@W[0:4] + nn1b ; += a@W[4:196]  (a now dead)
  gemm_f32<false, false, false, true ><<<g1, 256, 0, stream>>>(x, P[17],           P[18],   h1, BN, 252, 4);
  gemm_f32<false, false, true,  false><<<g1, 256, 0, stream>>>(A, P[17] + 4 * 252, nullptr, h1, BN, 252, 192);
  // c = edge(b) -> A
  edge_layer(Bb, 192, P[9], P[10], P[11], P[12], A, 252);
  // h1 += b@W[196:388]  (b now dead)
  gemm_f32<false, false, true, false><<<g1, 256, 0, stream>>>(Bb, P[17] + 196 * 252, nullptr, h1, BN, 252, 192);
  // d = edge(c) -> B
  edge_layer(A, 192, P[13], P[14], P[15], P[16], Bb, 252);
  // h1 += c@W[388:580] ; += d@W[580:772]
  gemm_f32<false, false, true, false><<<g1, 256, 0, stream>>>(A,  P[17] + 388 * 252, nullptr, h1, BN, 252, 192);
  gemm_f32<false, false, true, false><<<g1, 256, 0, stream>>>(Bb, P[17] + 580 * 252, nullptr, h1, BN, 252, 192);

  // nn2: h2 = leaky(h1) @ nn2w + nn2b  -> A
  dim3 g2(192 / 64, BN / 64);
  gemm_f32<true, false, false, true><<<g2, 256, 0, stream>>>(h1, P[19], P[20], A, BN, 192, 252);

  pool_kernel<<<B_, 192, 0, stream>>>(A, pooled);
  head_kernel<<<B_, 128, 0, stream>>>(pooled, P[21], P[22], P[23], P[24], (float*)d_out);
}

// Round 3
// 3100.176 us; speedup vs baseline: 1.7401x; 1.7401x over previous
//
#include <hip/hip_runtime.h>
#include <cstdint>
#include <cstddef>

#define LK(x) ((x) > 0.f ? (x) : 0.01f * (x))

constexpr int B_ = 256;
constexpr int N_ = 256;
constexpr int BN = B_ * N_;
constexpr int KNN = 4;
constexpr int CHUNK_B = 64;                 // batches per UV chunk
constexpr int CHUNK_ROWS = CHUNK_B * N_;    // 16384 rows

// ---------------- KNN: one block per batch, one thread per point ----------------
__global__ void knn_kernel(const float* __restrict__ feat, int F, int* __restrict__ idxout) {
  __shared__ float px[N_], py[N_], pz[N_];
  int b = blockIdx.x, t = threadIdx.x;
  const float* row = feat + ((size_t)b * N_ + t) * F;
  px[t] = row[0]; py[t] = row[1]; pz[t] = row[2];
  __syncthreads();
  float x = px[t], y = py[t], z = pz[t];
  float bd0 = INFINITY, bd1 = INFINITY, bd2 = INFINITY, bd3 = INFINITY;
  int bi0 = 0, bi1 = 0, bi2 = 0, bi3 = 0;
  for (int j = 0; j < N_; ++j) {
    #pragma clang fp contract(off)
    float dx = x - px[j], dy = y - py[j], dz = z - pz[j];
    float d = (dx * dx + dy * dy) + dz * dz;
    if (j == t) continue;                 // self excluded (eye -> inf)
    if (d < bd3) {                        // strict <  == top_k lower-index tie-break
      if (d < bd2) {
        bd3 = bd2; bi3 = bi2;
        if (d < bd1) {
          bd2 = bd1; bi2 = bi1;
          if (d < bd0) { bd1 = bd0; bi1 = bi0; bd0 = d; bi0 = j; }
          else         { bd1 = d; bi1 = j; }
        } else         { bd2 = d; bi2 = j; }
      } else           { bd3 = d; bi3 = j; }
    }
  }
  int* o = idxout + ((size_t)b * N_ + t) * KNN;
  o[0] = bi0; o[1] = bi1; o[2] = bi2; o[3] = bi3;
}

// -------- prep: wcat = [w1_top - w1_bot | w1_bot] (F x 2H1), bcat = [b1 | 0] --------
__global__ void prep_uvw(const float* __restrict__ w1, const float* __restrict__ b1,
                         int F, int H1, float* __restrict__ wcat, float* __restrict__ bcat) {
  int t = blockIdx.x * 256 + threadIdx.x;
  int FH = F * H1;
  if (t < FH) {
    int k = t / H1, c = t - k * H1;
    float top = w1[(size_t)k * H1 + c];
    float bot = w1[(size_t)(F + k) * H1 + c];
    wcat[(size_t)k * 2 * H1 + c]      = top - bot;
    wcat[(size_t)k * 2 * H1 + H1 + c] = bot;
  }
  if (t < H1) { bcat[t] = b1[t]; bcat[H1 + t] = 0.f; }
}

// -------- tiled fp32 GEMM: C (+)= act?(A) @ W (+ bias) --------
// BM=128, BN=64, BK=16, 256 threads, 8x4 micro-tile. M must be multiple of 128.
template<bool ACT_A, bool ACCUM, bool HAS_BIAS>
__global__ __launch_bounds__(256) void gemm_f32(
    const float* __restrict__ A, const float* __restrict__ W,
    const float* __restrict__ bias, float* __restrict__ C,
    int M, int N, int K) {
  __shared__ float sA[16][132];
  __shared__ float sW[16][68];
  int tid = threadIdx.x;
  int m0 = blockIdx.y * 128;
  int n0 = blockIdx.x * 64;
  int kkA = tid & 15, mA = tid >> 4;
  int nW = tid & 63, kW = tid >> 6;
  int ty = tid >> 4, tx = tid & 15;
  float acc[8][4] = {};
  for (int k0 = 0; k0 < K; k0 += 16) {
    int kg = k0 + kkA;
    #pragma unroll
    for (int i = 0; i < 8; ++i) {
      int m = mA + i * 16;
      float v = 0.f;
      if (kg < K) {
        v = A[(size_t)(m0 + m) * K + kg];
        if (ACT_A) v = LK(v);
      }
      sA[kkA][m] = v;
    }
    #pragma unroll
    for (int q = 0; q < 4; ++q) {
      int kk = kW + q * 4;
      int kgw = k0 + kk, n = n0 + nW;
      float v = 0.f;
      if (kgw < K && n < N) v = W[(size_t)kgw * N + n];
      sW[kk][nW] = v;
    }
    __syncthreads();
    #pragma unroll
    for (int kk = 0; kk < 16; ++kk) {
      float4 a0 = *(const float4*)&sA[kk][ty * 8];
      float4 a1 = *(const float4*)&sA[kk][ty * 8 + 4];
      float4 w  = *(const float4*)&sW[kk][tx * 4];
      float av[8] = {a0.x, a0.y, a0.z, a0.w, a1.x, a1.y, a1.z, a1.w};
      float wv[4] = {w.x, w.y, w.z, w.w};
      #pragma unroll
      for (int i = 0; i < 8; ++i)
        #pragma unroll
        for (int j = 0; j < 4; ++j)
          acc[i][j] += av[i] * wv[j];
    }
    __syncthreads();
  }
  int n = n0 + tx * 4;
  float bv[4] = {0.f, 0.f, 0.f, 0.f};
  if (HAS_BIAS) {
    #pragma unroll
    for (int j = 0; j < 4; ++j) if (n + j < N) bv[j] = bias[n + j];
  }
  #pragma unroll
  for (int i = 0; i < 8; ++i) {
    size_t m = (size_t)(m0 + ty * 8 + i);
    if (n + 3 < N) {
      float4 o;
      o.x = acc[i][0] + bv[0]; o.y = acc[i][1] + bv[1];
      o.z = acc[i][2] + bv[2]; o.w = acc[i][3] + bv[3];
      float4* cp = (float4*)(C + m * N + n);
      if (ACCUM) { float4 c = *cp; o.x += c.x; o.y += c.y; o.z += c.z; o.w += c.w; }
      *cp = o;
    } else {
      #pragma unroll
      for (int j = 0; j < 4; ++j) {
        if (n + j < N) {
          float v = acc[i][j] + bv[j];
          size_t off = m * N + n + j;
          if (ACCUM) v += C[off];
          C[off] = v;
        }
      }
    }
  }
}

// -------- segmented-A GEMM (3 row-major segments concatenated along K) --------
template<bool ACCUM, bool HAS_BIAS>
__global__ __launch_bounds__(256) void gemm_seg3(
    const float* __restrict__ A0, int w0, const float* __restrict__ A1, int w1,
    const float* __restrict__ A2, int w2, const float* __restrict__ W,
    const float* __restrict__ bias, float* __restrict__ C, int M, int N) {
  const int K = w0 + w1 + w2;
  __shared__ float sA[16][132];
  __shared__ float sW[16][68];
  int tid = threadIdx.x;
  int m0 = blockIdx.y * 128;
  int n0 = blockIdx.x * 64;
  int kkA = tid & 15, mA = tid >> 4;
  int nW = tid & 63, kW = tid >> 6;
  int ty = tid >> 4, tx = tid & 15;
  float acc[8][4] = {};
  for (int k0 = 0; k0 < K; k0 += 16) {
    int kg = k0 + kkA;
    #pragma unroll
    for (int i = 0; i < 8; ++i) {
      int row = m0 + mA + i * 16;
      float v = 0.f;
      if (kg < K) {
        int s = kg;
        if (s < w0)            v = A0[(size_t)row * w0 + s];
        else if ((s -= w0) < w1) v = A1[(size_t)row * w1 + s];
        else                   v = A2[(size_t)row * w2 + (s - w1)];
      }
      sA[kkA][mA + i * 16] = v;
    }
    #pragma unroll
    for (int q = 0; q < 4; ++q) {
      int kk = kW + q * 4;
      int kgw = k0 + kk, n = n0 + nW;
      float v = 0.f;
      if (kgw < K && n < N) v = W[(size_t)kgw * N + n];
      sW[kk][nW] = v;
    }
    __syncthreads();
    #pragma unroll
    for (int kk = 0; kk < 16; ++kk) {
      float4 a0 = *(const float4*)&sA[kk][ty * 8];
      float4 a1 = *(const float4*)&sA[kk][ty * 8 + 4];
      float4 w  = *(const float4*)&sW[kk][tx * 4];
      float av[8] = {a0.x, a0.y, a0.z, a0.w, a1.x, a1.y, a1.z, a1.w};
      float wv[4] = {w.x, w.y, w.z, w.w};
      #pragma unroll
      for (int i = 0; i < 8; ++i)
        #pragma unroll
        for (int j = 0; j < 4; ++j)
          acc[i][j] += av[i] * wv[j];
    }
    __syncthreads();
  }
  int n = n0 + tx * 4;
  float bv[4] = {0.f, 0.f, 0.f, 0.f};
  if (HAS_BIAS) {
    #pragma unroll
    for (int j = 0; j < 4; ++j) if (n + j < N) bv[j] = bias[n + j];
  }
  #pragma unroll
  for (int i = 0; i < 8; ++i) {
    size_t m = (size_t)(m0 + ty * 8 + i);
    if (n + 3 < N) {
      float4 o;
      o.x = acc[i][0] + bv[0]; o.y = acc[i][1] + bv[1];
      o.z = acc[i][2] + bv[2]; o.w = acc[i][3] + bv[3];
      float4* cp = (float4*)(C + m * N + n);
      if (ACCUM) { float4 c = *cp; o.x += c.x; o.y += c.y; o.z += c.z; o.w += c.w; }
      *cp = o;
    } else {
      #pragma unroll
      for (int j = 0; j < 4; ++j) {
        if (n + j < N) {
          float v = acc[i][j] + bv[j];
          size_t off = m * N + n + j;
          if (ACCUM) v += C[off];
          C[off] = v;
        }
      }
    }
  }
}

// ---------------- fused edge stage 2, K-tiled ----------------
// h1[edge] = leaky(U[i] + V[j]) (b1 folded into U); out[i] = sum_k leaky(h1 @ w2 + b2)
// Block = 16 points (64 edge rows) x all 192 cols; K tiled by 16.
__global__ __launch_bounds__(256) void edge_stage2(
    const float* __restrict__ UV, const int* __restrict__ idx,
    const float* __restrict__ w2, const float* __restrict__ b2,
    float* __restrict__ out, int H1) {
  __shared__ float sH[16][68];
  __shared__ float sW[16][196];
  __shared__ int sJ[64];
  int tid = threadIdx.x;
  int g0 = blockIdx.x * 16;           // chunk-local first point (16 | 256: one batch/block)
  int bbase = (g0 >> 8) << 8;
  if (tid < 64) sJ[tid] = bbase + idx[(size_t)g0 * 4 + tid];
  int W2 = H1 * 2;                    // UV row stride
  int r = tid >> 2, seg = tid & 3;    // staging coords: edge row r, 4-col segment
  int gp_r = g0 + (r >> 2);
  int ty = tid >> 4, tx = tid & 15;   // compute coords
  int gp = g0 + ty;
  float acc[4][12] = {};
  int nKt = (H1 + 15) >> 4;
  for (int kt = 0; kt < nKt; ++kt) {
    int k0 = kt << 4;
    __syncthreads();
    // stage sH[kk][row]: 64 rows x 16 k-cols
    {
      int c = k0 + (seg << 2);
      const float* up = UV + (size_t)gp_r * W2 + c;
      const float* vp = UV + (size_t)sJ[r] * W2 + H1 + c;
      float u[4], v[4];
      if (c + 3 < H1) {
        float4 uu = *(const float4*)up; float4 vv = *(const float4*)vp;
        u[0] = uu.x; u[1] = uu.y; u[2] = uu.z; u[3] = uu.w;
        v[0] = vv.x; v[1] = vv.y; v[2] = vv.z; v[3] = vv.w;
      } else {
        #pragma unroll
        for (int j = 0; j < 4; ++j) {
          u[j] = (c + j < H1) ? up[j] : 0.f;
          v[j] = (c + j < H1) ? vp[j] : 0.f;
        }
      }
      #pragma unroll
      for (int j = 0; j < 4; ++j) {
        float t = u[j] + v[j];
        sH[(seg << 2) + j][r] = (c + j < H1) ? LK(t) : 0.f;
      }
    }
    // stage sW: 16 x 192 = 768 float4s; thread does 3
    #pragma unroll
    for (int p = 0; p < 3; ++p) {
      int q = tid + (p << 8);
      int kk = q / 48;
      int c4 = q - kk * 48;
      int k = k0 + kk;
      float4 wv = {0.f, 0.f, 0.f, 0.f};
      if (k < H1) wv = *(const float4*)(w2 + (size_t)k * 192 + (c4 << 2));
      *(float4*)&sW[kk][c4 << 2] = wv;
    }
    __syncthreads();
    #pragma unroll
    for (int kk = 0; kk < 16; ++kk) {
      float4 a = *(const float4*)&sH[kk][ty << 2];
      float av[4] = {a.x, a.y, a.z, a.w};
      #pragma unroll
      for (int ct = 0; ct < 3; ++ct) {
        float4 w = *(const float4*)&sW[kk][ct * 64 + (tx << 2)];
        float wv[4] = {w.x, w.y, w.z, w.w};
        #pragma unroll
        for (int i = 0; i < 4; ++i)
          #pragma unroll
          for (int j = 0; j < 4; ++j)
            acc[i][ct * 4 + j] += av[i] * wv[j];
      }
    }
  }
  #pragma unroll
  for (int ct = 0; ct < 3; ++ct) {
    float o[4];
    #pragma unroll
    for (int j = 0; j < 4; ++j) {
      int col = ct * 64 + (tx << 2) + j;
      float bvv = b2[col];
      float s = 0.f;
      #pragma unroll
      for (int i = 0; i < 4; ++i) {
        float t = acc[i][ct * 4 + j] + bvv;
        s += LK(t);
      }
      o[j] = s;
    }
    float4 ov = {o[0], o[1], o[2], o[3]};
    *(float4*)(out + (size_t)gp * 192 + ct * 64 + (tx << 2)) = ov;
  }
}

// ---------------- pooling: max/min/sum/mean over N, then leaky ----------------
__global__ void pool_kernel(const float* __restrict__ h, float* __restrict__ pooled) {
  int b = blockIdx.x, ch = threadIdx.x;  // 192 threads
  const float* p = h + (size_t)b * N_ * 192 + ch;
  float mx = -INFINITY, mn = INFINITY, sm = 0.f;
  for (int n = 0; n < N_; ++n) {
    float v = p[(size_t)n * 192];
    mx = fmaxf(mx, v); mn = fminf(mn, v); sm += v;
  }
  float* o = pooled + (size_t)b * 768;
  o[ch]       = LK(mx);
  o[192 + ch] = LK(mn);
  o[384 + ch] = LK(sm);
  float mean = sm * (1.f / 256.f);
  o[576 + ch] = LK(mean);
}

// ---------------- head: nn3 (768->96) + leaky + nn4 (96->1) ----------------
__global__ void head_kernel(const float* __restrict__ pooled,
                            const float* __restrict__ w3, const float* __restrict__ b3,
                            const float* __restrict__ w4, const float* __restrict__ b4,
                            float* __restrict__ out) {
  __shared__ float sp[768];
  __shared__ float st[96];
  int b = blockIdx.x, t = threadIdx.x;   // 128 threads
  for (int c = t; c < 768; c += 128) sp[c] = pooled[(size_t)b * 768 + c];
  __syncthreads();
  if (t < 96) {
    float s = b3[t];
    for (int r = 0; r < 768; ++r) s += sp[r] * w3[(size_t)r * 96 + t];
    s = LK(s);
    st[t] = s * w4[t];
  }
  __syncthreads();
  if (t == 0) {
    float s = b4[0];
    for (int i = 0; i < 96; ++i) s += st[i];
    out[b] = s;
  }
}

extern "C" void kernel_launch(void* const* d_in, const int* in_sizes, int n_in,
                              void* d_out, int out_size, void* d_ws, size_t ws_size,
                              hipStream_t stream) {
  (void)in_sizes; (void)n_in; (void)out_size; (void)ws_size;
  const float* x = (const float*)d_in[0];
  const float* P[25];
  for (int i = 0; i < 25; ++i) P[i] = (const float*)d_in[i];

  // ---- workspace layout (peak ~202.1 MB) ----
  char* ws = (char*)d_ws;
  int*   idx    = (int*)  (ws + 0);            //  1,048,576
  float* A      = (float*)(ws + 1048576);      // 50,331,648  (a, then c, then h2)
  float* Bb     = (float*)(ws + 51380224);     // 50,331,648  (b, then d)
  float* h1     = (float*)(ws + 101711872);    // 66,060,288
  float* UV     = (float*)(ws + 167772160);    // 33,030,144  (chunk, [U|V] stride 2*H1)
  float* pooled = (float*)(ws + 200802304);    //    786,432
  float* wcat   = (float*)(ws + 201588736);    //    508,032
  float* bcat   = (float*)(ws + 202096768);    //      2,016

  auto edge_layer = [&](const float* src, int F, const float* w1, const float* b1,
                        const float* w2, const float* b2, float* dst, int H1) {
    knn_kernel<<<B_, N_, 0, stream>>>(src, F, idx);
    int W2 = 2 * H1;
    prep_uvw<<<(F * H1 + 255) / 256, 256, 0, stream>>>(w1, b1, F, H1, wcat, bcat);
    dim3 gUV((W2 + 63) / 64, CHUNK_ROWS / 128);
    for (int cb = 0; cb < B_; cb += CHUNK_B) {
      size_t base = (size_t)cb * N_;
      // UV = src @ [wdiff | w1_bot] + [b1 | 0]
      gemm_f32<false, false, true><<<gUV, 256, 0, stream>>>(src + base * F, wcat, bcat, UV, CHUNK_ROWS, W2, F);
      edge_stage2<<<CHUNK_ROWS / 16, 256, 0, stream>>>(UV, idx + base * 4, w2, b2, dst + base * 192, H1);
    }
  };

  // a = edge(x) -> A ; b = edge(a) -> Bb
  edge_layer(x,  4,   P[1], P[2], P[3], P[4], A,  96);
  edge_layer(A,  192, P[5], P[6], P[7], P[8], Bb, 252);
  // h1 = [x,a,b] @ nn1w[0:388] + nn1b
  {
    dim3 g((252 + 63) / 64, BN / 128);
    gemm_seg3<false, true><<<g, 256, 0, stream>>>(x, 4, A, 192, Bb, 192, P[17], P[18], h1, BN, 252);
  }
  // c = edge(b) -> A ; d = edge(c) -> Bb
  edge_layer(Bb, 192, P[9],  P[10], P[11], P[12], A,  252);
  edge_layer(A,  192, P[13], P[14], P[15], P[16], Bb, 252);
  // h1 += [c,d] @ nn1w[388:772]
  {
    dim3 g((252 + 63) / 64, BN / 128);
    gemm_seg3<true, false><<<g, 256, 0, stream>>>(A, 192, Bb, 192, Bb, 0, P[17] + (size_t)388 * 252, nullptr, h1, BN, 252);
  }
  // nn2: h2 = leaky(h1) @ nn2w + nn2b -> A
  {
    dim3 g(192 / 64, BN / 128);
    gemm_f32<true, false, true><<<g, 256, 0, stream>>>(h1, P[19], P[20], A, BN, 192, 252);
  }
  pool_kernel<<<B_, 192, 0, stream>>>(A, pooled);
  head_kernel<<<B_, 128, 0, stream>>>(pooled, P[21], P[22], P[23], P[24], (float*)d_out);
}